// Round 1
// baseline (840.211 us; speedup 1.0000x reference)
//
#include <hip/hip_runtime.h>
#include <cstdint>
#include <cstddef>

#define E_ 8
#define D_ 768
#define F_ 3072
#define N_ 16384
#define CAP_ 2560   // int(1.25 * 16384 / 8)

typedef __attribute__((ext_vector_type(8))) short bf16x8;
typedef __attribute__((ext_vector_type(4))) float f32x4;

__device__ __forceinline__ unsigned short f2bf(float f) {
  unsigned u = __float_as_uint(f);
  u += 0x7fffu + ((u >> 16) & 1u);   // round-to-nearest-even
  return (unsigned short)(u >> 16);
}

__device__ __forceinline__ void gload16(const void* g, void* l) {
  __builtin_amdgcn_global_load_lds(
      (const __attribute__((address_space(1))) void*)g,
      (__attribute__((address_space(3))) void*)l, 16, 0, 0);
}

// ---------------- cast x fp32 -> bf16 ----------------
__global__ void cast_x_kernel(const float* __restrict__ x, unsigned short* __restrict__ xb) {
  int i = blockIdx.x * 256 + threadIdx.x;       // 4 elements per thread
  float4 v = reinterpret_cast<const float4*>(x)[i];
  ushort4 o;
  o.x = f2bf(v.x); o.y = f2bf(v.y); o.z = f2bf(v.z); o.w = f2bf(v.w);
  reinterpret_cast<ushort4*>(xb)[i] = o;
}

// ---------------- transpose + cast weights: src [E][R][C] fp32 -> dst [E][C][R] bf16 ----------------
__global__ void tcast_kernel(const float* __restrict__ src, unsigned short* __restrict__ dst,
                             int R, int C) {
  __shared__ float tile[32][33];
  int e = blockIdx.z;
  const float* s = src + (size_t)e * R * C;
  unsigned short* d = dst + (size_t)e * R * C;
  int c0 = blockIdx.x * 32, r0 = blockIdx.y * 32;
  int tx = threadIdx.x, ty = threadIdx.y;
  #pragma unroll
  for (int rr = ty; rr < 32; rr += 8)
    tile[rr][tx] = s[(size_t)(r0 + rr) * C + c0 + tx];
  __syncthreads();
  #pragma unroll
  for (int cc = ty; cc < 32; cc += 8)
    d[(size_t)(c0 + cc) * R + r0 + tx] = f2bf(tile[tx][cc]);
}

// ---------------- router: fp32 logits, softmax-max, argmax ----------------
__global__ __launch_bounds__(256) void router_kernel(
    const float* __restrict__ x, const float* __restrict__ sw, const float* __restrict__ sb,
    int* __restrict__ route, float* __restrict__ prob, int* __restrict__ counts) {
  __shared__ float wl[E_ * D_];   // transposed: wl[e][d] -> stride-1 in d (2-way bank, free)
  int tid = threadIdx.x;
  for (int idx = tid; idx < E_ * D_; idx += 256) {
    int dd = idx >> 3, ee = idx & 7;
    wl[ee * D_ + dd] = sw[idx];
  }
  __syncthreads();
  int wave = tid >> 6, lane = tid & 63;
  for (int t = blockIdx.x * 4 + wave; t < N_; t += gridDim.x * 4) {
    const float* xp = x + (size_t)t * D_;
    float acc[E_];
    #pragma unroll
    for (int e = 0; e < E_; ++e) acc[e] = 0.f;
    #pragma unroll
    for (int r = 0; r < D_ / 64; ++r) {
      int dd = r * 64 + lane;
      float xv = xp[dd];
      #pragma unroll
      for (int e = 0; e < E_; ++e) acc[e] += xv * wl[e * D_ + dd];
    }
    #pragma unroll
    for (int e = 0; e < E_; ++e) {
      #pragma unroll
      for (int o = 32; o > 0; o >>= 1) acc[e] += __shfl_xor(acc[e], o);
    }
    if (lane == 0) {
      float mx = -1e30f; int arg = 0;
      #pragma unroll
      for (int e = 0; e < E_; ++e) {
        float l = acc[e] + sb[e];
        acc[e] = l;
        if (l > mx) { mx = l; arg = e; }   // strict > : first index on ties (np argmax)
      }
      float s = 0.f;
      #pragma unroll
      for (int e = 0; e < E_; ++e) s += expf(acc[e] - mx);
      route[t] = arg;
      prob[t] = 1.f / s;                   // = max softmax prob
      atomicAdd(&counts[arg], 1);
    }
  }
}

// ---------------- slot assignment (+ exact priority-drop fallback) ----------------
__global__ void assign_kernel(const int* __restrict__ route, const float* __restrict__ prob,
                              const int* __restrict__ counts, int* __restrict__ cursor,
                              int* __restrict__ tok_list, int* __restrict__ slot) {
  int i = blockIdx.x * 256 + threadIdx.x;
  if (i >= N_) return;
  int e = route[i];
  int c = counts[e];
  int s; bool keep;
  if (c <= CAP_) {
    // no drops in this expert: any bijective slot assignment is equivalent
    s = atomicAdd(&cursor[e], 1);
    keep = true;
  } else {
    // exact rank: tokens sorted by desc prob, stable by index (matches lexsort)
    float p = prob[i];
    int r = 0;
    for (int j = 0; j < N_; ++j) {
      if (route[j] == e) {
        float pj = prob[j];
        r += (pj > p || (pj == p && j < i)) ? 1 : 0;
      }
    }
    s = r; keep = (r < CAP_);
  }
  if (keep) tok_list[e * CAP_ + s] = i;
  slot[i] = keep ? s : -1;
}

// ---------------- GEMM1: h[e][m][f] = gelu( x[tok] @ w1[e] + b1[e] ), bf16 MFMA ----------------
__global__ __launch_bounds__(256) void gemm1_kernel(
    const unsigned short* __restrict__ xb, const unsigned short* __restrict__ w1t,
    const float* __restrict__ b1, const int* __restrict__ tok_list,
    const int* __restrict__ counts, unsigned short* __restrict__ hb) {
  int e = blockIdx.z;
  int Me = counts[e] < CAP_ ? counts[e] : CAP_;
  int m0 = blockIdx.x * 128;
  if (m0 >= Me) return;
  int n0 = blockIdx.y * 128;
  __shared__ unsigned short At[128 * 32];
  __shared__ unsigned short Bt[128 * 32];
  int tid = threadIdx.x, lane = tid & 63, wave = tid >> 6;
  int rA0 = (wave * 2 + 0) * 16 + (lane >> 2);
  int rA1 = (wave * 2 + 1) * 16 + (lane >> 2);
  int cb = (lane & 3) * 16;   // byte offset within 64B row
  int tok0 = tok_list[e * CAP_ + m0 + rA0];
  int tok1 = tok_list[e * CAP_ + m0 + rA1];
  const char* gA0 = (const char*)(xb + (size_t)tok0 * D_) + cb;
  const char* gA1 = (const char*)(xb + (size_t)tok1 * D_) + cb;
  const char* gB0 = (const char*)(w1t + ((size_t)e * F_ + n0 + rA0) * D_) + cb;
  const char* gB1 = (const char*)(w1t + ((size_t)e * F_ + n0 + rA1) * D_) + cb;
  unsigned short* lA0 = At + (wave * 2 + 0) * 512;
  unsigned short* lA1 = At + (wave * 2 + 1) * 512;
  unsigned short* lB0 = Bt + (wave * 2 + 0) * 512;
  unsigned short* lB1 = Bt + (wave * 2 + 1) * 512;
  f32x4 acc[4][4] = {};
  int wm = (wave >> 1) * 64, wn = (wave & 1) * 64;
  int fr = lane & 15, fk = (lane >> 4) * 8;
  for (int k0 = 0; k0 < D_; k0 += 32) {
    __syncthreads();
    gload16(gA0 + (size_t)2 * k0, lA0);
    gload16(gA1 + (size_t)2 * k0, lA1);
    gload16(gB0 + (size_t)2 * k0, lB0);
    gload16(gB1 + (size_t)2 * k0, lB1);
    __syncthreads();
    bf16x8 a[4], b[4];
    #pragma unroll
    for (int i = 0; i < 4; ++i)
      a[i] = *(const bf16x8*)(At + (wm + i * 16 + fr) * 32 + fk);
    #pragma unroll
    for (int j = 0; j < 4; ++j)
      b[j] = *(const bf16x8*)(Bt + (wn + j * 16 + fr) * 32 + fk);
    #pragma unroll
    for (int i = 0; i < 4; ++i)
      #pragma unroll
      for (int j = 0; j < 4; ++j)
        acc[i][j] = __builtin_amdgcn_mfma_f32_16x16x32_bf16(a[i], b[j], acc[i][j], 0, 0, 0);
  }
  int q4 = (lane >> 4) * 4;
  #pragma unroll
  for (int i = 0; i < 4; ++i) {
    #pragma unroll
    for (int j = 0; j < 4; ++j) {
      int col = n0 + wn + j * 16 + (lane & 15);
      float bias = b1[e * F_ + col];
      #pragma unroll
      for (int r = 0; r < 4; ++r) {
        int row = m0 + wm + i * 16 + q4 + r;
        if (row < Me) {
          float v = acc[i][j][r] + bias;
          v = 0.5f * v * (1.f + erff(v * 0.70710678118654752f));   // exact GELU
          hb[((size_t)e * CAP_ + row) * F_ + col] = f2bf(v);
        }
      }
    }
  }
}

// ---------------- GEMM2: out[tok] = (h[e] @ w2[e] + b2[e]) * prob[tok] ----------------
__global__ __launch_bounds__(256) void gemm2_kernel(
    const unsigned short* __restrict__ hb, const unsigned short* __restrict__ w2t,
    const float* __restrict__ b2, const int* __restrict__ tok_list,
    const int* __restrict__ counts, const float* __restrict__ prob,
    float* __restrict__ out) {
  int e = blockIdx.z;
  int Me = counts[e] < CAP_ ? counts[e] : CAP_;
  int m0 = blockIdx.x * 128;
  if (m0 >= Me) return;
  int n0 = blockIdx.y * 128;
  __shared__ unsigned short At[128 * 32];
  __shared__ unsigned short Bt[128 * 32];
  int tid = threadIdx.x, lane = tid & 63, wave = tid >> 6;
  int rA0 = (wave * 2 + 0) * 16 + (lane >> 2);
  int rA1 = (wave * 2 + 1) * 16 + (lane >> 2);
  int cb = (lane & 3) * 16;
  const char* gA0 = (const char*)(hb + ((size_t)e * CAP_ + m0 + rA0) * F_) + cb;
  const char* gA1 = (const char*)(hb + ((size_t)e * CAP_ + m0 + rA1) * F_) + cb;
  const char* gB0 = (const char*)(w2t + ((size_t)e * D_ + n0 + rA0) * F_) + cb;
  const char* gB1 = (const char*)(w2t + ((size_t)e * D_ + n0 + rA1) * F_) + cb;
  unsigned short* lA0 = At + (wave * 2 + 0) * 512;
  unsigned short* lA1 = At + (wave * 2 + 1) * 512;
  unsigned short* lB0 = Bt + (wave * 2 + 0) * 512;
  unsigned short* lB1 = Bt + (wave * 2 + 1) * 512;
  f32x4 acc[4][4] = {};
  int wm = (wave >> 1) * 64, wn = (wave & 1) * 64;
  int fr = lane & 15, fk = (lane >> 4) * 8;
  for (int k0 = 0; k0 < F_; k0 += 32) {
    __syncthreads();
    gload16(gA0 + (size_t)2 * k0, lA0);
    gload16(gA1 + (size_t)2 * k0, lA1);
    gload16(gB0 + (size_t)2 * k0, lB0);
    gload16(gB1 + (size_t)2 * k0, lB1);
    __syncthreads();
    bf16x8 a[4], b[4];
    #pragma unroll
    for (int i = 0; i < 4; ++i)
      a[i] = *(const bf16x8*)(At + (wm + i * 16 + fr) * 32 + fk);
    #pragma unroll
    for (int j = 0; j < 4; ++j)
      b[j] = *(const bf16x8*)(Bt + (wn + j * 16 + fr) * 32 + fk);
    #pragma unroll
    for (int i = 0; i < 4; ++i)
      #pragma unroll
      for (int j = 0; j < 4; ++j)
        acc[i][j] = __builtin_amdgcn_mfma_f32_16x16x32_bf16(a[i], b[j], acc[i][j], 0, 0, 0);
  }
  int q4 = (lane >> 4) * 4;
  #pragma unroll
  for (int i = 0; i < 4; ++i) {
    #pragma unroll
    for (int r = 0; r < 4; ++r) {
      int row = m0 + wm + i * 16 + q4 + r;
      if (row < Me) {
        int tok = tok_list[e * CAP_ + row];
        float pm = prob[tok];
        #pragma unroll
        for (int j = 0; j < 4; ++j) {
          int col = n0 + wn + j * 16 + (lane & 15);
          float v = (acc[i][j][r] + b2[e * D_ + col]) * pm;
          out[(size_t)tok * D_ + col] = v;
        }
      }
    }
  }
}

// ---------------- passthrough for dropped tokens ----------------
__global__ void passthrough_kernel(const float* __restrict__ x, const float* __restrict__ prob,
                                   const int* __restrict__ slot, float* __restrict__ out) {
  int t = blockIdx.x;
  if (slot[t] >= 0) return;
  float p = prob[t];
  for (int d = threadIdx.x; d < D_; d += 256)
    out[(size_t)t * D_ + d] = x[(size_t)t * D_ + d] * p;
}

extern "C" void kernel_launch(void* const* d_in, const int* in_sizes, int n_in,
                              void* d_out, int out_size, void* d_ws, size_t ws_size,
                              hipStream_t stream) {
  const float* x  = (const float*)d_in[0];
  const float* sw = (const float*)d_in[1];
  const float* sb = (const float*)d_in[2];
  const float* w1 = (const float*)d_in[3];
  const float* b1 = (const float*)d_in[4];
  const float* w2 = (const float*)d_in[5];
  const float* b2 = (const float*)d_in[6];
  float* out = (float*)d_out;
  (void)in_sizes; (void)n_in; (void)out_size; (void)ws_size;

  char* ws = (char*)d_ws;
  size_t off = 0;
  auto alloc = [&](size_t bytes) {
    char* p = ws + off;
    off = (off + bytes + 255) & ~(size_t)255;
    return p;
  };
  int* meta    = (int*)alloc((size_t)(64 + E_ * CAP_) * sizeof(int));
  int* counts  = meta;
  int* cursor  = meta + 32;
  int* tok_list = meta + 64;
  int* route   = (int*)alloc((size_t)N_ * 4);
  float* prob  = (float*)alloc((size_t)N_ * 4);
  int* slot    = (int*)alloc((size_t)N_ * 4);
  unsigned short* xb  = (unsigned short*)alloc((size_t)N_ * D_ * 2);
  unsigned short* w1t = (unsigned short*)alloc((size_t)E_ * D_ * F_ * 2);
  unsigned short* w2t = (unsigned short*)alloc((size_t)E_ * D_ * F_ * 2);
  unsigned short* hb  = (unsigned short*)alloc((size_t)E_ * CAP_ * F_ * 2);

  hipMemsetAsync(meta, 0, (size_t)(64 + E_ * CAP_) * sizeof(int), stream);

  cast_x_kernel<<<(N_ * D_ / 4) / 256, 256, 0, stream>>>(x, xb);
  dim3 tb(32, 8);
  tcast_kernel<<<dim3(F_ / 32, D_ / 32, E_), tb, 0, stream>>>(w1, w1t, D_, F_);
  tcast_kernel<<<dim3(D_ / 32, F_ / 32, E_), tb, 0, stream>>>(w2, w2t, F_, D_);
  router_kernel<<<256, 256, 0, stream>>>(x, sw, sb, route, prob, counts);
  assign_kernel<<<N_ / 256, 256, 0, stream>>>(route, prob, counts, cursor, tok_list, slot);
  gemm1_kernel<<<dim3(CAP_ / 128, F_ / 128, E_), 256, 0, stream>>>(xb, w1t, b1, tok_list, counts, hb);
  gemm2_kernel<<<dim3(CAP_ / 128, D_ / 128, E_), 256, 0, stream>>>(hb, w2t, b2, tok_list, counts, prob, out);
  passthrough_kernel<<<N_, 256, 0, stream>>>(x, prob, slot, out);
}

// Round 2
// 813.372 us; speedup vs baseline: 1.0330x; 1.0330x over previous
//
#include <hip/hip_runtime.h>
#include <cstdint>
#include <cstddef>

#define E_ 8
#define D_ 768
#define F_ 3072
#define N_ 16384
#define CAP_ 2560   // int(1.25 * 16384 / 8)

typedef __attribute__((ext_vector_type(8))) short bf16x8;
typedef __attribute__((ext_vector_type(4))) float f32x4;

__device__ __forceinline__ unsigned short f2bf(float f) {
  unsigned u = __float_as_uint(f);
  u += 0x7fffu + ((u >> 16) & 1u);   // round-to-nearest-even
  return (unsigned short)(u >> 16);
}

__device__ __forceinline__ void gload16(const void* g, void* l) {
  __builtin_amdgcn_global_load_lds(
      (const __attribute__((address_space(1))) void*)g,
      (__attribute__((address_space(3))) void*)l, 16, 0, 0);
}

// ---------------- transpose + cast weights: src [E][R][C] fp32 -> dst [E][C][R] bf16 ----------------
// block (32,8); 64x64 tile; ushort2 stores (full write-bus utilization)
__global__ void tcast_kernel(const float* __restrict__ src, unsigned short* __restrict__ dst,
                             int R, int C) {
  __shared__ float tile[64][65];
  int e = blockIdx.z;
  const float* s = src + (size_t)e * R * C;
  unsigned short* d = dst + (size_t)e * R * C;
  int c0 = blockIdx.x * 64, r0 = blockIdx.y * 64;
  int tx = threadIdx.x, ty = threadIdx.y;
  #pragma unroll
  for (int rr = ty; rr < 64; rr += 8) {
    tile[rr][tx]      = s[(size_t)(r0 + rr) * C + c0 + tx];
    tile[rr][tx + 32] = s[(size_t)(r0 + rr) * C + c0 + tx + 32];
  }
  __syncthreads();
  #pragma unroll
  for (int cc = ty; cc < 64; cc += 8) {
    ushort2 o;
    o.x = f2bf(tile[2 * tx][cc]);       // LDS stride 2*65 between lanes -> 2-way, free
    o.y = f2bf(tile[2 * tx + 1][cc]);
    *(ushort2*)&d[(size_t)(c0 + cc) * R + r0 + 2 * tx] = o;
  }
}

// ---------------- router (fused x->bf16 cast): fp32 logits, softmax-max, argmax ----------------
// wave per token group: 1024 blocks x 4 waves x 4 tokens = 16384
__global__ __launch_bounds__(256) void router_kernel(
    const float* __restrict__ x, const float* __restrict__ sw, const float* __restrict__ sb,
    int* __restrict__ route, float* __restrict__ prob, int* __restrict__ counts,
    unsigned short* __restrict__ xb) {
  __shared__ float wl[E_ * D_];   // transposed: wl[e][d] -> stride-1 in d (2-way bank, free)
  int tid = threadIdx.x;
  for (int idx = tid; idx < E_ * D_; idx += 256) {
    int dd = idx >> 3, ee = idx & 7;
    wl[ee * D_ + dd] = sw[idx];
  }
  __syncthreads();
  int wave = tid >> 6, lane = tid & 63;
  int tbase = blockIdx.x * 16 + wave * 4;
  #pragma unroll
  for (int tt = 0; tt < 4; ++tt) {
    int t = tbase + tt;
    const float* xp = x + (size_t)t * D_;
    unsigned short* xbp = xb + (size_t)t * D_;
    float acc[E_];
    #pragma unroll
    for (int e = 0; e < E_; ++e) acc[e] = 0.f;
    #pragma unroll
    for (int r = 0; r < D_ / 64; ++r) {
      int dd = r * 64 + lane;
      float xv = xp[dd];
      xbp[dd] = f2bf(xv);               // fused cast
      #pragma unroll
      for (int e = 0; e < E_; ++e) acc[e] += xv * wl[e * D_ + dd];
    }
    #pragma unroll
    for (int e = 0; e < E_; ++e) {
      #pragma unroll
      for (int o = 32; o > 0; o >>= 1) acc[e] += __shfl_xor(acc[e], o);
    }
    if (lane == 0) {
      float mx = -1e30f; int arg = 0;
      #pragma unroll
      for (int e = 0; e < E_; ++e) {
        float l = acc[e] + sb[e];
        acc[e] = l;
        if (l > mx) { mx = l; arg = e; }   // strict > : first index on ties (np argmax)
      }
      float s = 0.f;
      #pragma unroll
      for (int e = 0; e < E_; ++e) s += expf(acc[e] - mx);
      route[t] = arg;
      prob[t] = 1.f / s;                   // = max softmax prob
      atomicAdd(&counts[arg], 1);
    }
  }
}

// ---------------- slot assignment (+ exact priority-drop fallback) ----------------
__global__ void assign_kernel(const int* __restrict__ route, const float* __restrict__ prob,
                              const int* __restrict__ counts, int* __restrict__ cursor,
                              int* __restrict__ tok_list, int* __restrict__ slot) {
  int i = blockIdx.x * 256 + threadIdx.x;
  if (i >= N_) return;
  int e = route[i];
  int c = counts[e];
  int s; bool keep;
  if (c <= CAP_) {
    // no drops in this expert: any bijective slot assignment is equivalent
    s = atomicAdd(&cursor[e], 1);
    keep = true;
  } else {
    // exact rank: tokens sorted by desc prob, stable by index (matches lexsort)
    float p = prob[i];
    int r = 0;
    for (int j = 0; j < N_; ++j) {
      if (route[j] == e) {
        float pj = prob[j];
        r += (pj > p || (pj == p && j < i)) ? 1 : 0;
      }
    }
    s = r; keep = (r < CAP_);
  }
  if (keep) tok_list[e * CAP_ + s] = i;
  slot[i] = keep ? s : -1;
}

// ---------------- GEMM1: h[e][m][f] = gelu( x[tok] @ w1[e] + b1[e] ), bf16 MFMA ----------------
__global__ __launch_bounds__(256) void gemm1_kernel(
    const unsigned short* __restrict__ xb, const unsigned short* __restrict__ w1t,
    const float* __restrict__ b1, const int* __restrict__ tok_list,
    const int* __restrict__ counts, unsigned short* __restrict__ hb) {
  int e = blockIdx.z;
  int Me = counts[e] < CAP_ ? counts[e] : CAP_;
  int m0 = blockIdx.x * 128;
  if (m0 >= Me) return;
  int n0 = blockIdx.y * 128;
  __shared__ unsigned short At[128 * 32];
  __shared__ unsigned short Bt[128 * 32];
  int tid = threadIdx.x, lane = tid & 63, wave = tid >> 6;
  int rA0 = (wave * 2 + 0) * 16 + (lane >> 2);
  int rA1 = (wave * 2 + 1) * 16 + (lane >> 2);
  int cb = (lane & 3) * 16;   // byte offset within 64B row
  int tok0 = tok_list[e * CAP_ + m0 + rA0];
  int tok1 = tok_list[e * CAP_ + m0 + rA1];
  const char* gA0 = (const char*)(xb + (size_t)tok0 * D_) + cb;
  const char* gA1 = (const char*)(xb + (size_t)tok1 * D_) + cb;
  const char* gB0 = (const char*)(w1t + ((size_t)e * F_ + n0 + rA0) * D_) + cb;
  const char* gB1 = (const char*)(w1t + ((size_t)e * F_ + n0 + rA1) * D_) + cb;
  unsigned short* lA0 = At + (wave * 2 + 0) * 512;
  unsigned short* lA1 = At + (wave * 2 + 1) * 512;
  unsigned short* lB0 = Bt + (wave * 2 + 0) * 512;
  unsigned short* lB1 = Bt + (wave * 2 + 1) * 512;
  f32x4 acc[4][4] = {};
  int wm = (wave >> 1) * 64, wn = (wave & 1) * 64;
  int fr = lane & 15, fk = (lane >> 4) * 8;
  for (int k0 = 0; k0 < D_; k0 += 32) {
    __syncthreads();
    gload16(gA0 + (size_t)2 * k0, lA0);
    gload16(gA1 + (size_t)2 * k0, lA1);
    gload16(gB0 + (size_t)2 * k0, lB0);
    gload16(gB1 + (size_t)2 * k0, lB1);
    __syncthreads();
    bf16x8 a[4], b[4];
    #pragma unroll
    for (int i = 0; i < 4; ++i)
      a[i] = *(const bf16x8*)(At + (wm + i * 16 + fr) * 32 + fk);
    #pragma unroll
    for (int j = 0; j < 4; ++j)
      b[j] = *(const bf16x8*)(Bt + (wn + j * 16 + fr) * 32 + fk);
    #pragma unroll
    for (int i = 0; i < 4; ++i)
      #pragma unroll
      for (int j = 0; j < 4; ++j)
        acc[i][j] = __builtin_amdgcn_mfma_f32_16x16x32_bf16(a[i], b[j], acc[i][j], 0, 0, 0);
  }
  int q4 = (lane >> 4) * 4;
  #pragma unroll
  for (int i = 0; i < 4; ++i) {
    #pragma unroll
    for (int j = 0; j < 4; ++j) {
      int col = n0 + wn + j * 16 + (lane & 15);
      float bias = b1[e * F_ + col];
      #pragma unroll
      for (int r = 0; r < 4; ++r) {
        int row = m0 + wm + i * 16 + q4 + r;
        if (row < Me) {
          float v = acc[i][j][r] + bias;
          v = 0.5f * v * (1.f + erff(v * 0.70710678118654752f));   // exact GELU
          hb[((size_t)e * CAP_ + row) * F_ + col] = f2bf(v);
        }
      }
    }
  }
}

// ---------------- GEMM2: out[tok] = (h[e] @ w2[e] + b2[e]) * prob[tok] ----------------
__global__ __launch_bounds__(256) void gemm2_kernel(
    const unsigned short* __restrict__ hb, const unsigned short* __restrict__ w2t,
    const float* __restrict__ b2, const int* __restrict__ tok_list,
    const int* __restrict__ counts, const float* __restrict__ prob,
    float* __restrict__ out) {
  int e = blockIdx.z;
  int Me = counts[e] < CAP_ ? counts[e] : CAP_;
  int m0 = blockIdx.x * 128;
  if (m0 >= Me) return;
  int n0 = blockIdx.y * 128;
  __shared__ unsigned short At[128 * 32];
  __shared__ unsigned short Bt[128 * 32];
  int tid = threadIdx.x, lane = tid & 63, wave = tid >> 6;
  int rA0 = (wave * 2 + 0) * 16 + (lane >> 2);
  int rA1 = (wave * 2 + 1) * 16 + (lane >> 2);
  int cb = (lane & 3) * 16;
  const char* gA0 = (const char*)(hb + ((size_t)e * CAP_ + m0 + rA0) * F_) + cb;
  const char* gA1 = (const char*)(hb + ((size_t)e * CAP_ + m0 + rA1) * F_) + cb;
  const char* gB0 = (const char*)(w2t + ((size_t)e * D_ + n0 + rA0) * F_) + cb;
  const char* gB1 = (const char*)(w2t + ((size_t)e * D_ + n0 + rA1) * F_) + cb;
  unsigned short* lA0 = At + (wave * 2 + 0) * 512;
  unsigned short* lA1 = At + (wave * 2 + 1) * 512;
  unsigned short* lB0 = Bt + (wave * 2 + 0) * 512;
  unsigned short* lB1 = Bt + (wave * 2 + 1) * 512;
  f32x4 acc[4][4] = {};
  int wm = (wave >> 1) * 64, wn = (wave & 1) * 64;
  int fr = lane & 15, fk = (lane >> 4) * 8;
  for (int k0 = 0; k0 < F_; k0 += 32) {
    __syncthreads();
    gload16(gA0 + (size_t)2 * k0, lA0);
    gload16(gA1 + (size_t)2 * k0, lA1);
    gload16(gB0 + (size_t)2 * k0, lB0);
    gload16(gB1 + (size_t)2 * k0, lB1);
    __syncthreads();
    bf16x8 a[4], b[4];
    #pragma unroll
    for (int i = 0; i < 4; ++i)
      a[i] = *(const bf16x8*)(At + (wm + i * 16 + fr) * 32 + fk);
    #pragma unroll
    for (int j = 0; j < 4; ++j)
      b[j] = *(const bf16x8*)(Bt + (wn + j * 16 + fr) * 32 + fk);
    #pragma unroll
    for (int i = 0; i < 4; ++i)
      #pragma unroll
      for (int j = 0; j < 4; ++j)
        acc[i][j] = __builtin_amdgcn_mfma_f32_16x16x32_bf16(a[i], b[j], acc[i][j], 0, 0, 0);
  }
  int q4 = (lane >> 4) * 4;
  #pragma unroll
  for (int i = 0; i < 4; ++i) {
    #pragma unroll
    for (int r = 0; r < 4; ++r) {
      int row = m0 + wm + i * 16 + q4 + r;
      if (row < Me) {
        int tok = tok_list[e * CAP_ + row];
        float pm = prob[tok];
        #pragma unroll
        for (int j = 0; j < 4; ++j) {
          int col = n0 + wn + j * 16 + (lane & 15);
          float v = (acc[i][j][r] + b2[e * D_ + col]) * pm;
          out[(size_t)tok * D_ + col] = v;
        }
      }
    }
  }
}

// ---------------- passthrough for dropped tokens ----------------
__global__ void passthrough_kernel(const float* __restrict__ x, const float* __restrict__ prob,
                                   const int* __restrict__ slot, float* __restrict__ out) {
  int t = blockIdx.x;
  if (slot[t] >= 0) return;
  float p = prob[t];
  for (int d = threadIdx.x; d < D_; d += 256)
    out[(size_t)t * D_ + d] = x[(size_t)t * D_ + d] * p;
}

extern "C" void kernel_launch(void* const* d_in, const int* in_sizes, int n_in,
                              void* d_out, int out_size, void* d_ws, size_t ws_size,
                              hipStream_t stream) {
  const float* x  = (const float*)d_in[0];
  const float* sw = (const float*)d_in[1];
  const float* sb = (const float*)d_in[2];
  const float* w1 = (const float*)d_in[3];
  const float* b1 = (const float*)d_in[4];
  const float* w2 = (const float*)d_in[5];
  const float* b2 = (const float*)d_in[6];
  float* out = (float*)d_out;
  (void)in_sizes; (void)n_in; (void)out_size; (void)ws_size;

  char* ws = (char*)d_ws;
  size_t off = 0;
  auto alloc = [&](size_t bytes) {
    char* p = ws + off;
    off = (off + bytes + 255) & ~(size_t)255;
    return p;
  };
  int* meta    = (int*)alloc((size_t)(64 + E_ * CAP_) * sizeof(int));
  int* counts  = meta;
  int* cursor  = meta + 32;
  int* tok_list = meta + 64;
  int* route   = (int*)alloc((size_t)N_ * 4);
  float* prob  = (float*)alloc((size_t)N_ * 4);
  int* slot    = (int*)alloc((size_t)N_ * 4);
  unsigned short* xb  = (unsigned short*)alloc((size_t)N_ * D_ * 2);
  unsigned short* w1t = (unsigned short*)alloc((size_t)E_ * D_ * F_ * 2);
  unsigned short* w2t = (unsigned short*)alloc((size_t)E_ * D_ * F_ * 2);
  unsigned short* hb  = (unsigned short*)alloc((size_t)E_ * CAP_ * F_ * 2);

  hipMemsetAsync(meta, 0, (size_t)(64 + E_ * CAP_) * sizeof(int), stream);

  dim3 tb(32, 8);
  tcast_kernel<<<dim3(F_ / 64, D_ / 64, E_), tb, 0, stream>>>(w1, w1t, D_, F_);
  tcast_kernel<<<dim3(D_ / 64, F_ / 64, E_), tb, 0, stream>>>(w2, w2t, F_, D_);
  router_kernel<<<N_ / 16, 256, 0, stream>>>(x, sw, sb, route, prob, counts, xb);
  assign_kernel<<<N_ / 256, 256, 0, stream>>>(route, prob, counts, cursor, tok_list, slot);
  gemm1_kernel<<<dim3(CAP_ / 128, F_ / 128, E_), 256, 0, stream>>>(xb, w1t, b1, tok_list, counts, hb);
  gemm2_kernel<<<dim3(CAP_ / 128, D_ / 128, E_), 256, 0, stream>>>(hb, w2t, b2, tok_list, counts, prob, out);
  passthrough_kernel<<<N_, 256, 0, stream>>>(x, prob, slot, out);
}

// Round 4
// 590.851 us; speedup vs baseline: 1.4220x; 1.3766x over previous
//
#include <hip/hip_runtime.h>
#include <cstdint>
#include <cstddef>

#define E_ 8
#define D_ 768
#define F_ 3072
#define N_ 16384
#define CAP_ 2560   // int(1.25 * 16384 / 8)
#define NCHUNK_ (N_ / 256)   // 64

typedef __attribute__((ext_vector_type(8))) short bf16x8;
typedef __attribute__((ext_vector_type(4))) float f32x4;

__device__ __forceinline__ unsigned short f2bf(float f) {
  unsigned u = __float_as_uint(f);
  u += 0x7fffu + ((u >> 16) & 1u);   // round-to-nearest-even
  return (unsigned short)(u >> 16);
}

__device__ __forceinline__ void gload16(const void* g, void* l) {
  __builtin_amdgcn_global_load_lds(
      (const __attribute__((address_space(1))) void*)g,
      (__attribute__((address_space(3))) void*)l, 16, 0, 0);
}

// ---------------- transpose + cast weights: src [E][R][C] fp32 -> dst [E][C][R] bf16 ----------------
__global__ void tcast_kernel(const float* __restrict__ src, unsigned short* __restrict__ dst,
                             int R, int C) {
  __shared__ float tile[64][65];
  int e = blockIdx.z;
  const float* s = src + (size_t)e * R * C;
  unsigned short* d = dst + (size_t)e * R * C;
  int c0 = blockIdx.x * 64, r0 = blockIdx.y * 64;
  int tx = threadIdx.x, ty = threadIdx.y;
  #pragma unroll
  for (int rr = ty; rr < 64; rr += 8) {
    tile[rr][tx]      = s[(size_t)(r0 + rr) * C + c0 + tx];
    tile[rr][tx + 32] = s[(size_t)(r0 + rr) * C + c0 + tx + 32];
  }
  __syncthreads();
  #pragma unroll
  for (int cc = ty; cc < 64; cc += 8) {
    ushort2 o;
    o.x = f2bf(tile[2 * tx][cc]);       // LDS stride 2*65 between lanes -> 2-way, free
    o.y = f2bf(tile[2 * tx + 1][cc]);
    *(ushort2*)&d[(size_t)(c0 + cc) * R + r0 + 2 * tx] = o;
  }
}

// ---------------- router (fused x->bf16 cast): NO global atomics ----------------
__global__ __launch_bounds__(256) void router_kernel(
    const float* __restrict__ x, const float* __restrict__ sw, const float* __restrict__ sb,
    int* __restrict__ route, float* __restrict__ prob,
    unsigned short* __restrict__ xb) {
  __shared__ float wl[E_ * D_];   // wl[e][d], stride-1 in d
  int tid = threadIdx.x;
  // conflict-free LDS writes (consecutive lanes -> consecutive dd)
  #pragma unroll
  for (int ee = 0; ee < E_; ++ee)
    for (int dd = tid; dd < D_; dd += 256)
      wl[ee * D_ + dd] = sw[dd * E_ + ee];
  __syncthreads();
  int wave = tid >> 6, lane = tid & 63;
  int tbase = blockIdx.x * 16 + wave * 4;
  #pragma unroll
  for (int tt = 0; tt < 4; ++tt) {
    int t = tbase + tt;
    const float* xp = x + (size_t)t * D_;
    unsigned short* xbp = xb + (size_t)t * D_;
    float acc[E_];
    #pragma unroll
    for (int e = 0; e < E_; ++e) acc[e] = 0.f;
    #pragma unroll
    for (int r = 0; r < D_ / 64; ++r) {
      int dd = r * 64 + lane;
      float xv = xp[dd];
      xbp[dd] = f2bf(xv);               // fused cast
      #pragma unroll
      for (int e = 0; e < E_; ++e) acc[e] += xv * wl[e * D_ + dd];
    }
    #pragma unroll
    for (int e = 0; e < E_; ++e) {
      #pragma unroll
      for (int o = 32; o > 0; o >>= 1) acc[e] += __shfl_xor(acc[e], o);
    }
    if (lane == 0) {
      float mx = -1e30f; int arg = 0;
      #pragma unroll
      for (int e = 0; e < E_; ++e) {
        float l = acc[e] + sb[e];
        acc[e] = l;
        if (l > mx) { mx = l; arg = e; }   // strict > : first index on ties (np argmax)
      }
      float s = 0.f;
      #pragma unroll
      for (int e = 0; e < E_; ++e) s += expf(acc[e] - mx);
      route[t] = arg;
      prob[t] = 1.f / s;                   // = max softmax prob
    }
  }
}

// ---------------- per-chunk histogram (LDS atomics only) ----------------
__global__ void hist_kernel(const int* __restrict__ route, int* __restrict__ chunk_hist) {
  __shared__ int h[E_];
  int tid = threadIdx.x;
  if (tid < E_) h[tid] = 0;
  __syncthreads();
  atomicAdd(&h[route[blockIdx.x * 256 + tid]], 1);
  __syncthreads();
  if (tid < E_) chunk_hist[blockIdx.x * E_ + tid] = h[tid];
}

// ---------------- exclusive scan over chunks per expert (single tiny block) ----------------
__global__ void scan_kernel(const int* __restrict__ chunk_hist, int* __restrict__ chunk_off,
                            int* __restrict__ counts) {
  __shared__ int h[NCHUNK_ * E_];
  int tid = threadIdx.x;
  h[tid] = chunk_hist[tid];          // 512 threads, 512 values
  __syncthreads();
  if (tid < E_) {
    int run = 0;
    for (int c = 0; c < NCHUNK_; ++c) {
      chunk_off[c * E_ + tid] = run;
      run += h[c * E_ + tid];
    }
    counts[tid] = run;
  }
}

// ---------------- slot assignment: deterministic, atomic-free ----------------
__global__ void assign_kernel(const int* __restrict__ route, const float* __restrict__ prob,
                              const int* __restrict__ counts, const int* __restrict__ chunk_off,
                              int* __restrict__ tok_list, int* __restrict__ slot) {
  __shared__ int rt[256];
  int tid = threadIdx.x;
  int i = blockIdx.x * 256 + tid;
  int e = route[i];
  rt[tid] = e;
  __syncthreads();
  int r = 0;
  for (int j = 0; j < tid; ++j) r += (rt[j] == e) ? 1 : 0;   // broadcast reads, conflict-free
  int c = counts[e];
  int s; bool keep;
  if (c <= CAP_) {
    s = chunk_off[blockIdx.x * E_ + e] + r;   // bijective slot in [0, c)
    keep = true;
  } else {
    // exact rank: tokens sorted by desc prob, stable by index (matches lexsort)
    float p = prob[i];
    int rr = 0;
    for (int j = 0; j < N_; ++j) {
      if (route[j] == e) {
        float pj = prob[j];
        rr += (pj > p || (pj == p && j < i)) ? 1 : 0;
      }
    }
    s = rr; keep = (rr < CAP_);
  }
  if (keep) tok_list[e * CAP_ + s] = i;
  slot[i] = keep ? s : -1;
}

// ---------------- GEMM1: h[e][m][f] = gelu( x[tok] @ w1[e] + b1[e] ), bf16 MFMA ----------------
__global__ __launch_bounds__(256) void gemm1_kernel(
    const unsigned short* __restrict__ xb, const unsigned short* __restrict__ w1t,
    const float* __restrict__ b1, const int* __restrict__ tok_list,
    const int* __restrict__ counts, unsigned short* __restrict__ hb) {
  int e = blockIdx.z;
  int Me = counts[e] < CAP_ ? counts[e] : CAP_;
  int m0 = blockIdx.x * 128;
  if (m0 >= Me) return;
  int n0 = blockIdx.y * 128;
  __shared__ unsigned short At[128 * 32];
  __shared__ unsigned short Bt[128 * 32];
  int tid = threadIdx.x, lane = tid & 63, wave = tid >> 6;
  int rA0 = (wave * 2 + 0) * 16 + (lane >> 2);
  int rA1 = (wave * 2 + 1) * 16 + (lane >> 2);
  int cb = (lane & 3) * 16;   // byte offset within 64B row
  // clamp staging rows to Me-1: tok_list beyond Me is UNINITIALIZED (0xAA poison);
  // rows >= Me are discarded at the guarded store, so redundant loads are fine.
  int mr0 = m0 + rA0; if (mr0 > Me - 1) mr0 = Me - 1;
  int mr1 = m0 + rA1; if (mr1 > Me - 1) mr1 = Me - 1;
  int tok0 = tok_list[e * CAP_ + mr0];
  int tok1 = tok_list[e * CAP_ + mr1];
  const char* gA0 = (const char*)(xb + (size_t)tok0 * D_) + cb;
  const char* gA1 = (const char*)(xb + (size_t)tok1 * D_) + cb;
  const char* gB0 = (const char*)(w1t + ((size_t)e * F_ + n0 + rA0) * D_) + cb;
  const char* gB1 = (const char*)(w1t + ((size_t)e * F_ + n0 + rA1) * D_) + cb;
  unsigned short* lA0 = At + (wave * 2 + 0) * 512;
  unsigned short* lA1 = At + (wave * 2 + 1) * 512;
  unsigned short* lB0 = Bt + (wave * 2 + 0) * 512;
  unsigned short* lB1 = Bt + (wave * 2 + 1) * 512;
  f32x4 acc[4][4] = {};
  int wm = (wave >> 1) * 64, wn = (wave & 1) * 64;
  int fr = lane & 15, fk = (lane >> 4) * 8;
  for (int k0 = 0; k0 < D_; k0 += 32) {
    __syncthreads();
    gload16(gA0 + (size_t)2 * k0, lA0);
    gload16(gA1 + (size_t)2 * k0, lA1);
    gload16(gB0 + (size_t)2 * k0, lB0);
    gload16(gB1 + (size_t)2 * k0, lB1);
    __syncthreads();
    bf16x8 a[4], b[4];
    #pragma unroll
    for (int i = 0; i < 4; ++i)
      a[i] = *(const bf16x8*)(At + (wm + i * 16 + fr) * 32 + fk);
    #pragma unroll
    for (int j = 0; j < 4; ++j)
      b[j] = *(const bf16x8*)(Bt + (wn + j * 16 + fr) * 32 + fk);
    #pragma unroll
    for (int i = 0; i < 4; ++i)
      #pragma unroll
      for (int j = 0; j < 4; ++j)
        acc[i][j] = __builtin_amdgcn_mfma_f32_16x16x32_bf16(a[i], b[j], acc[i][j], 0, 0, 0);
  }
  int q4 = (lane >> 4) * 4;
  #pragma unroll
  for (int i = 0; i < 4; ++i) {
    #pragma unroll
    for (int j = 0; j < 4; ++j) {
      int col = n0 + wn + j * 16 + (lane & 15);
      float bias = b1[e * F_ + col];
      #pragma unroll
      for (int r = 0; r < 4; ++r) {
        int row = m0 + wm + i * 16 + q4 + r;
        if (row < Me) {
          float v = acc[i][j][r] + bias;
          v = 0.5f * v * (1.f + erff(v * 0.70710678118654752f));   // exact GELU
          hb[((size_t)e * CAP_ + row) * F_ + col] = f2bf(v);
        }
      }
    }
  }
}

// ---------------- GEMM2: out[tok] = (h[e] @ w2[e] + b2[e]) * prob[tok] ----------------
__global__ __launch_bounds__(256) void gemm2_kernel(
    const unsigned short* __restrict__ hb, const unsigned short* __restrict__ w2t,
    const float* __restrict__ b2, const int* __restrict__ tok_list,
    const int* __restrict__ counts, const float* __restrict__ prob,
    float* __restrict__ out) {
  int e = blockIdx.z;
  int Me = counts[e] < CAP_ ? counts[e] : CAP_;
  int m0 = blockIdx.x * 128;
  if (m0 >= Me) return;
  int n0 = blockIdx.y * 128;
  __shared__ unsigned short At[128 * 32];
  __shared__ unsigned short Bt[128 * 32];
  int tid = threadIdx.x, lane = tid & 63, wave = tid >> 6;
  int rA0 = (wave * 2 + 0) * 16 + (lane >> 2);
  int rA1 = (wave * 2 + 1) * 16 + (lane >> 2);
  int cb = (lane & 3) * 16;
  // hb rows beyond Me are in-bounds (CAP_ rows allocated); poison values are
  // discarded by the row<Me store guard, so no clamp needed here.
  const char* gA0 = (const char*)(hb + ((size_t)e * CAP_ + m0 + rA0) * F_) + cb;
  const char* gA1 = (const char*)(hb + ((size_t)e * CAP_ + m0 + rA1) * F_) + cb;
  const char* gB0 = (const char*)(w2t + ((size_t)e * D_ + n0 + rA0) * F_) + cb;
  const char* gB1 = (const char*)(w2t + ((size_t)e * D_ + n0 + rA1) * F_) + cb;
  unsigned short* lA0 = At + (wave * 2 + 0) * 512;
  unsigned short* lA1 = At + (wave * 2 + 1) * 512;
  unsigned short* lB0 = Bt + (wave * 2 + 0) * 512;
  unsigned short* lB1 = Bt + (wave * 2 + 1) * 512;
  f32x4 acc[4][4] = {};
  int wm = (wave >> 1) * 64, wn = (wave & 1) * 64;
  int fr = lane & 15, fk = (lane >> 4) * 8;
  for (int k0 = 0; k0 < F_; k0 += 32) {
    __syncthreads();
    gload16(gA0 + (size_t)2 * k0, lA0);
    gload16(gA1 + (size_t)2 * k0, lA1);
    gload16(gB0 + (size_t)2 * k0, lB0);
    gload16(gB1 + (size_t)2 * k0, lB1);
    __syncthreads();
    bf16x8 a[4], b[4];
    #pragma unroll
    for (int i = 0; i < 4; ++i)
      a[i] = *(const bf16x8*)(At + (wm + i * 16 + fr) * 32 + fk);
    #pragma unroll
    for (int j = 0; j < 4; ++j)
      b[j] = *(const bf16x8*)(Bt + (wn + j * 16 + fr) * 32 + fk);
    #pragma unroll
    for (int i = 0; i < 4; ++i)
      #pragma unroll
      for (int j = 0; j < 4; ++j)
        acc[i][j] = __builtin_amdgcn_mfma_f32_16x16x32_bf16(a[i], b[j], acc[i][j], 0, 0, 0);
  }
  int q4 = (lane >> 4) * 4;
  #pragma unroll
  for (int i = 0; i < 4; ++i) {
    #pragma unroll
    for (int r = 0; r < 4; ++r) {
      int row = m0 + wm + i * 16 + q4 + r;
      if (row < Me) {
        int tok = tok_list[e * CAP_ + row];
        float pm = prob[tok];
        #pragma unroll
        for (int j = 0; j < 4; ++j) {
          int col = n0 + wn + j * 16 + (lane & 15);
          float v = (acc[i][j][r] + b2[e * D_ + col]) * pm;
          out[(size_t)tok * D_ + col] = v;
        }
      }
    }
  }
}

// ---------------- passthrough for dropped tokens ----------------
__global__ void passthrough_kernel(const float* __restrict__ x, const float* __restrict__ prob,
                                   const int* __restrict__ slot, float* __restrict__ out) {
  int t = blockIdx.x;
  if (slot[t] >= 0) return;
  float p = prob[t];
  for (int d = threadIdx.x; d < D_; d += 256)
    out[(size_t)t * D_ + d] = x[(size_t)t * D_ + d] * p;
}

extern "C" void kernel_launch(void* const* d_in, const int* in_sizes, int n_in,
                              void* d_out, int out_size, void* d_ws, size_t ws_size,
                              hipStream_t stream) {
  const float* x  = (const float*)d_in[0];
  const float* sw = (const float*)d_in[1];
  const float* sb = (const float*)d_in[2];
  const float* w1 = (const float*)d_in[3];
  const float* b1 = (const float*)d_in[4];
  const float* w2 = (const float*)d_in[5];
  const float* b2 = (const float*)d_in[6];
  float* out = (float*)d_out;
  (void)in_sizes; (void)n_in; (void)out_size; (void)ws_size;

  char* ws = (char*)d_ws;
  size_t off = 0;
  auto alloc = [&](size_t bytes) {
    char* p = ws + off;
    off = (off + bytes + 255) & ~(size_t)255;
    return p;
  };
  int* counts     = (int*)alloc(32 * sizeof(int));
  int* chunk_hist = (int*)alloc((size_t)NCHUNK_ * E_ * sizeof(int));
  int* chunk_off  = (int*)alloc((size_t)NCHUNK_ * E_ * sizeof(int));
  int* tok_list   = (int*)alloc((size_t)E_ * CAP_ * sizeof(int));
  int* route      = (int*)alloc((size_t)N_ * 4);
  float* prob     = (float*)alloc((size_t)N_ * 4);
  int* slot       = (int*)alloc((size_t)N_ * 4);
  unsigned short* xb  = (unsigned short*)alloc((size_t)N_ * D_ * 2);
  unsigned short* w1t = (unsigned short*)alloc((size_t)E_ * D_ * F_ * 2);
  unsigned short* w2t = (unsigned short*)alloc((size_t)E_ * D_ * F_ * 2);
  unsigned short* hb  = (unsigned short*)alloc((size_t)E_ * CAP_ * F_ * 2);

  dim3 tb(32, 8);
  tcast_kernel<<<dim3(F_ / 64, D_ / 64, E_), tb, 0, stream>>>(w1, w1t, D_, F_);
  tcast_kernel<<<dim3(D_ / 64, F_ / 64, E_), tb, 0, stream>>>(w2, w2t, F_, D_);
  router_kernel<<<N_ / 16, 256, 0, stream>>>(x, sw, sb, route, prob, xb);
  hist_kernel<<<NCHUNK_, 256, 0, stream>>>(route, chunk_hist);
  scan_kernel<<<1, NCHUNK_ * E_, 0, stream>>>(chunk_hist, chunk_off, counts);
  assign_kernel<<<NCHUNK_, 256, 0, stream>>>(route, prob, counts, chunk_off, tok_list, slot);
  gemm1_kernel<<<dim3(CAP_ / 128, F_ / 128, E_), 256, 0, stream>>>(xb, w1t, b1, tok_list, counts, hb);
  gemm2_kernel<<<dim3(CAP_ / 128, D_ / 128, E_), 256, 0, stream>>>(hb, w2t, b2, tok_list, counts, prob, out);
  passthrough_kernel<<<N_, 256, 0, stream>>>(x, prob, slot, out);
}